// Round 1
// baseline (281.688 us; speedup 1.0000x reference)
//
#include <hip/hip_runtime.h>
#include <math.h>

#define NPTS 512
#define NBATCH 64
#define NROWS (NPTS * NBATCH)   // 32768
#define LARGEV 1000000.0f

// ---------------------------------------------------------------------------
// key_padding_mask dtype sniffer: jax bool may arrive as 1-byte bool, int32,
// or float32. Scan the first 32768 bytes (= full buffer in the bool case, so
// always in-bounds): word==0x3f800000 -> f32; word>1 -> packed bytes; else i32.
// ---------------------------------------------------------------------------
__global__ __launch_bounds__(256) void detect_kernel(const unsigned int* __restrict__ raw,
                                                     int* __restrict__ flag) {
  __shared__ int sF, sB;
  if (threadIdx.x == 0) { sF = 0; sB = 0; }
  __syncthreads();
  int f = 0, bg = 0;
  for (int t = threadIdx.x; t < (NROWS / 4); t += 256) {
    unsigned int w = raw[t];
    if (w == 0x3f800000u) f = 1;       // float 1.0f pattern (impossible for 0/1 bytes)
    else if (w > 1u) bg = 1;           // packed 0/1 bytes with a high byte set
  }
  if (f)  atomicOr(&sF, 1);
  if (bg) atomicOr(&sB, 1);
  __syncthreads();
  if (threadIdx.x == 0) flag[0] = sF ? 2 : (sB ? 1 : 0);  // 0=i32, 1=bytes, 2=f32
}

__global__ __launch_bounds__(256) void decode_kernel(const void* __restrict__ raw,
                                                     const int* __restrict__ flag,
                                                     unsigned char* __restrict__ mask) {
  int i = blockIdx.x * 256 + threadIdx.x;
  if (i >= NROWS) return;
  int f = flag[0];
  unsigned char m;
  if (f == 1)      m = ((const unsigned char*)raw)[i] ? 1 : 0;
  else if (f == 0) m = ((const int*)raw)[i] ? 1 : 0;
  else             m = (((const float*)raw)[i] != 0.0f) ? 1 : 0;
  mask[i] = m;
}

// ---------------------------------------------------------------------------
// Feature kernel: block = 64 rows (i) x 4 j-chunks; positions+mask in LDS.
// tid = il*4 + jc so the 4 chunk-partials for a row sit in adjacent lanes and
// reduce with shfl_xor(1), shfl_xor(2).
// Sector index replicates arctan2 octant semantics with compares only:
//   edges at k*pi/4; angle==pi (dy==+0, dx<0) falls in NO sector; angle==0 -> s=4.
// __f*_rn intrinsics forbid FMA contraction so dist matches numpy's
// sqrt((dx*dx + dy*dy) + 1e-8) bit-for-bit (threshold compares are exact).
// ---------------------------------------------------------------------------
__global__ __launch_bounds__(256) void feat_kernel(const float* __restrict__ pos,
                                                   const unsigned char* __restrict__ mask,
                                                   float* __restrict__ feat) {
  __shared__ float sx[NPTS], sy[NPTS];
  __shared__ unsigned char smk[NPTS];
  const int b  = blockIdx.x >> 3;
  const int i0 = (blockIdx.x & 7) << 6;
  const int tid = threadIdx.x;
  for (int t = tid; t < NPTS; t += 256) {
    float2 p = ((const float2*)pos)[b * NPTS + t];
    sx[t] = p.x; sy[t] = p.y;
    smk[t] = mask[b * NPTS + t];
  }
  __syncthreads();

  const int il = tid >> 2;       // row within block: 0..63
  const int jc = tid & 3;        // j-chunk: 0..3
  const int i  = i0 + il;
  const float xi = sx[i], yi = sy[i];

  float cnt[12];
#pragma unroll
  for (int k = 0; k < 12; ++k) cnt[k] = 0.0f;
  float dmin[3] = {LARGEV, LARGEV, LARGEV};
  float scnt[8], smin[8];
#pragma unroll
  for (int k = 0; k < 8; ++k) { scnt[k] = 0.0f; smin[k] = LARGEV; }
  float sumd = 0.0f, vcnt = 0.0f;

  const int jbeg = jc << 7;
  for (int jj = 0; jj < 128; ++jj) {
    const int j = jbeg + jj;
    const bool valid = (j != i) && (smk[j] == 0);
    // rel = pos[j] - pos[i]
    const float dx = __fsub_rn(sx[j], xi);
    const float dy = __fsub_rn(sy[j], yi);
    const float d2 = __fadd_rn(__fadd_rn(__fmul_rn(dx, dx), __fmul_rn(dy, dy)), 1e-8f);
    const float dist = __fsqrt_rn(d2);
    const float ady = fabsf(dy);
    const bool up = dx >  __fmul_rn(ady, 0.5f);
    const bool dn = dx < -__fmul_rn(ady, 0.5f);

    const float vm   = valid ? 1.0f : 0.0f;
    const float fup  = (valid && up) ? 1.0f : 0.0f;
    const float fdn  = (valid && dn) ? 1.0f : 0.0f;
    const float flat = (valid && !up && !dn) ? 1.0f : 0.0f;

    const float w3  = dist <  3.0f ? 1.0f : 0.0f;
    const float w5  = dist <  5.0f ? 1.0f : 0.0f;
    const float w8  = dist <  8.0f ? 1.0f : 0.0f;
    const float w12 = dist < 12.0f ? 1.0f : 0.0f;
    cnt[0] += w3 * fup;  cnt[1]  += w3 * fdn;  cnt[2]  += w3 * flat;
    cnt[3] += w5 * fup;  cnt[4]  += w5 * fdn;  cnt[5]  += w5 * flat;
    cnt[6] += w8 * fup;  cnt[7]  += w8 * fdn;  cnt[8]  += w8 * flat;
    cnt[9] += w12 * fup; cnt[10] += w12 * fdn; cnt[11] += w12 * flat;

    dmin[0] = fminf(dmin[0], fup  > 0.0f ? dist : LARGEV);
    dmin[1] = fminf(dmin[1], fdn  > 0.0f ? dist : LARGEV);
    dmin[2] = fminf(dmin[2], flat > 0.0f ? dist : LARGEV);

    sumd += vm * dist;
    vcnt += vm;

    // octant: edges [-pi,-3pi/4,...,pi]; angle=atan2(dy,dx)
    int s;
    if (dy > 0.0f)      s = (dx > 0.0f) ? ((dy < dx) ? 4 : 5) : ((-dx < dy) ? 6 : 7);
    else if (dy < 0.0f) s = (dx < 0.0f) ? ((dx < dy) ? 0 : 1) : ((dx < -dy) ? 2 : 3);
    else                s = (dx > 0.0f) ? 4 : -1;   // angle==0 -> s4; angle==pi -> none
    if (!valid) s = -1;
#pragma unroll
    for (int k = 0; k < 8; ++k) {
      const bool in_s = (s == k);
      scnt[k] += in_s ? 1.0f : 0.0f;
      smin[k] = fminf(smin[k], in_s ? dist : LARGEV);
    }
  }

  // reduce 4 chunk partials (lanes differing in bits 0..1)
#pragma unroll
  for (int k = 0; k < 12; ++k) { cnt[k] += __shfl_xor(cnt[k], 1); cnt[k] += __shfl_xor(cnt[k], 2); }
#pragma unroll
  for (int k = 0; k < 8; ++k)  { scnt[k] += __shfl_xor(scnt[k], 1); scnt[k] += __shfl_xor(scnt[k], 2); }
  sumd += __shfl_xor(sumd, 1); sumd += __shfl_xor(sumd, 2);
  vcnt += __shfl_xor(vcnt, 1); vcnt += __shfl_xor(vcnt, 2);
#pragma unroll
  for (int k = 0; k < 3; ++k)  { dmin[k] = fminf(dmin[k], __shfl_xor(dmin[k], 1)); dmin[k] = fminf(dmin[k], __shfl_xor(dmin[k], 2)); }
#pragma unroll
  for (int k = 0; k < 8; ++k)  { smin[k] = fminf(smin[k], __shfl_xor(smin[k], 1)); smin[k] = fminf(smin[k], __shfl_xor(smin[k], 2)); }

  if (jc == 0) {
    float* f = feat + (size_t)(b * NPTS + i) * 33;
#pragma unroll
    for (int k = 0; k < 12; ++k) f[k] = cnt[k];
    f[12] = fminf(dmin[0] / 10.0f, 1.0f);
    f[13] = fminf(dmin[1] / 10.0f, 1.0f);
    f[14] = fminf(dmin[2] / 10.0f, 1.0f);
#pragma unroll
    for (int k = 0; k < 8; ++k) {
      f[15 + 2 * k] = scnt[k];
      f[16 + 2 * k] = fminf(smin[k] / 10.0f, 1.0f);
    }
    f[31] = cnt[9] + cnt[10] + cnt[11];
    f[32] = fminf(sumd / fmaxf(vcnt, 1.0f) / 10.0f, 1.0f);
  }
}

// ---------------------------------------------------------------------------
// MLP: one wave per row, thread owns columns (2l, 2l+1). W1 staged in LDS,
// LN via wave shuffles only (64 lanes hold all 128 h's), exact-erf GELU,
// second GEMM reads W2 as float2 from global (L1-resident after warmup).
// hs[] is per-wave -> no inter-wave hazards -> no barriers in the row loop.
// ---------------------------------------------------------------------------
__global__ __launch_bounds__(256) void mlp_kernel(const float* __restrict__ feat,
    const float* __restrict__ W1, const float* __restrict__ b1,
    const float* __restrict__ gamma, const float* __restrict__ beta,
    const float* __restrict__ W2, const float* __restrict__ b2,
    float* __restrict__ out) {
  __shared__ float W1s[33 * 128];
  __shared__ float xs[64 * 33];
  __shared__ float hs[4][128];
  const int tid = threadIdx.x;
  for (int t = tid; t < 33 * 128; t += 256) W1s[t] = W1[t];
  const size_t r0 = (size_t)blockIdx.x * 64;
  for (int t = tid; t < 64 * 33; t += 256) xs[t] = feat[r0 * 33 + t];
  __syncthreads();

  const int w = tid >> 6;        // wave id -> row offset within group of 4
  const int l = tid & 63;        // lane
  const int e0 = l << 1;
  const float b1a = b1[e0],   b1b = b1[e0 + 1];
  const float ga  = gamma[e0], gb = gamma[e0 + 1];
  const float bea = beta[e0], beb = beta[e0 + 1];
  const float b2a = b2[e0],   b2b = b2[e0 + 1];
  const float2* __restrict__ W2v = (const float2*)W2;
  const float2* __restrict__ W1v = (const float2*)W1s;

  for (int it = 0; it < 16; ++it) {
    const int rl = it * 4 + w;
    const float* x = xs + rl * 33;
    float h0 = b1a, h1 = b1b;
#pragma unroll
    for (int k = 0; k < 33; ++k) {
      const float xv = x[k];
      const float2 wv = W1v[k * 64 + l];
      h0 += xv * wv.x;
      h1 += xv * wv.y;
    }
    // LayerNorm across 128 (two values per lane, 64 lanes)
    float s = h0 + h1;
#pragma unroll
    for (int o = 32; o > 0; o >>= 1) s += __shfl_xor(s, o);
    const float mu = s * 0.0078125f;
    const float d0 = h0 - mu, d1 = h1 - mu;
    float v = d0 * d0 + d1 * d1;
#pragma unroll
    for (int o = 32; o > 0; o >>= 1) v += __shfl_xor(v, o);
    const float var = v * 0.0078125f;
    const float inv = 1.0f / __fsqrt_rn(var + 1e-5f);
    float g0 = d0 * inv * ga + bea;
    float g1 = d1 * inv * gb + beb;
    // exact GELU: x * 0.5 * (1 + erf(x/sqrt(2)))
    g0 = 0.5f * g0 * (1.0f + erff(g0 * 0.70710678118654752f));
    g1 = 0.5f * g1 * (1.0f + erff(g1 * 0.70710678118654752f));
    hs[w][e0] = g0; hs[w][e0 + 1] = g1;   // per-wave row; in-wave LDS RAW is ordered

    float a0 = b2a, a1 = b2b;
#pragma unroll 4
    for (int k = 0; k < 128; ++k) {
      const float hk = hs[w][k];          // LDS broadcast
      const float2 wv = W2v[k * 64 + l];  // coalesced 512B per wave
      a0 += hk * wv.x;
      a1 += hk * wv.y;
    }
    ((float2*)out)[(r0 + rl) * 64 + l] = make_float2(a0, a1);
  }
}

extern "C" void kernel_launch(void* const* d_in, const int* in_sizes, int n_in,
                              void* d_out, int out_size, void* d_ws, size_t ws_size,
                              hipStream_t stream) {
  const float* positions = (const float*)d_in[0];
  const void*  kpm_raw   = d_in[1];
  const float* W1    = (const float*)d_in[2];
  const float* b1    = (const float*)d_in[3];
  const float* gamma = (const float*)d_in[4];
  const float* beta  = (const float*)d_in[5];
  const float* W2    = (const float*)d_in[6];
  const float* b2    = (const float*)d_in[7];
  float* out = (float*)d_out;

  char* ws = (char*)d_ws;
  int* flag = (int*)ws;                                   // 4 B
  unsigned char* mask = (unsigned char*)(ws + 256);       // 32768 B
  float* feat = (float*)(ws + 256 + NROWS);               // 32768*33*4 = 4.33 MB

  detect_kernel<<<1, 256, 0, stream>>>((const unsigned int*)kpm_raw, flag);
  decode_kernel<<<NROWS / 256, 256, 0, stream>>>(kpm_raw, flag, mask);
  feat_kernel<<<NBATCH * 8, 256, 0, stream>>>(positions, mask, feat);
  mlp_kernel<<<NROWS / 64, 256, 0, stream>>>(feat, W1, b1, gamma, beta, W2, b2, out);
}

// Round 2
// 208.342 us; speedup vs baseline: 1.3520x; 1.3520x over previous
//
#include <hip/hip_runtime.h>
#include <math.h>

#define NPTS 512
#define NBATCH 64
#define NROWS (NPTS * NBATCH)   // 32768
#define LARGEV 1000000.0f

// ---------------------------------------------------------------------------
// key_padding_mask dtype sniffer (jax bool may arrive as bytes / i32 / f32).
// ---------------------------------------------------------------------------
__global__ __launch_bounds__(256) void detect_kernel(const unsigned int* __restrict__ raw,
                                                     int* __restrict__ flag) {
  __shared__ int sF, sB;
  if (threadIdx.x == 0) { sF = 0; sB = 0; }
  __syncthreads();
  int f = 0, bg = 0;
  for (int t = threadIdx.x; t < (NROWS / 4); t += 256) {
    unsigned int w = raw[t];
    if (w == 0x3f800000u) f = 1;
    else if (w > 1u) bg = 1;
  }
  if (f)  atomicOr(&sF, 1);
  if (bg) atomicOr(&sB, 1);
  __syncthreads();
  if (threadIdx.x == 0) flag[0] = sF ? 2 : (sB ? 1 : 0);  // 0=i32, 1=bytes, 2=f32
}

__global__ __launch_bounds__(256) void decode_kernel(const void* __restrict__ raw,
                                                     const int* __restrict__ flag,
                                                     unsigned char* __restrict__ mask) {
  int i = blockIdx.x * 256 + threadIdx.x;
  if (i >= NROWS) return;
  int f = flag[0];
  unsigned char m;
  if (f == 1)      m = ((const unsigned char*)raw)[i] ? 1 : 0;
  else if (f == 0) m = ((const int*)raw)[i] ? 1 : 0;
  else             m = (((const float*)raw)[i] != 0.0f) ? 1 : 0;
  mask[i] = m;
}

// ---------------------------------------------------------------------------
// Feature kernel v2: block = 32 rows x 8 j-chunks (grid 1024 = 4 blocks/CU).
// j = jj*8 + jc puts the wave's 8 distinct LDS addresses on consecutive
// elements (conflict-free broadcast groups). Validity folded into dm.
// __f*_rn keeps dist bit-identical to numpy (threshold compares exact).
// ---------------------------------------------------------------------------
__global__ __launch_bounds__(256) void feat_kernel(const float* __restrict__ pos,
                                                   const unsigned char* __restrict__ mask,
                                                   float* __restrict__ feat) {
  __shared__ float2 sp[NPTS];
  __shared__ unsigned char smk[NPTS];
  const int b  = blockIdx.x >> 4;
  const int i0 = (blockIdx.x & 15) << 5;
  const int tid = threadIdx.x;
  for (int t = tid; t < NPTS; t += 256) {
    sp[t] = ((const float2*)pos)[b * NPTS + t];
    smk[t] = mask[b * NPTS + t];
  }
  __syncthreads();

  const int il = tid >> 3;       // row within block: 0..31
  const int jc = tid & 7;        // j-chunk: 0..7
  const int i  = i0 + il;
  const float2 pi = sp[i];

  float cnt[12];
#pragma unroll
  for (int k = 0; k < 12; ++k) cnt[k] = 0.0f;
  float dmin[3] = {LARGEV, LARGEV, LARGEV};
  float scnt[8], smin[8];
#pragma unroll
  for (int k = 0; k < 8; ++k) { scnt[k] = 0.0f; smin[k] = LARGEV; }
  float sumd = 0.0f, vcnt = 0.0f;

  for (int jj = 0; jj < 64; ++jj) {
    const int j = (jj << 3) + jc;
    const bool valid = (j != i) && (smk[j] == 0);
    const float2 pj = sp[j];
    const float dx = __fsub_rn(pj.x, pi.x);
    const float dy = __fsub_rn(pj.y, pi.y);
    const float d2 = __fadd_rn(__fadd_rn(__fmul_rn(dx, dx), __fmul_rn(dy, dy)), 1e-8f);
    const float dist = __fsqrt_rn(d2);
    const float dm = valid ? dist : LARGEV;   // masked distance (LARGE if invalid)
    const float ady = fabsf(dy);
    const bool up = dx >  __fmul_rn(ady, 0.5f);
    const bool dn = dx < -__fmul_rn(ady, 0.5f);
    const bool lat = !up && !dn;

    // dm < thresh implies valid (LARGE fails all thresholds)
    const bool w3  = dm <  3.0f;
    const bool w5  = dm <  5.0f;
    const bool w8  = dm <  8.0f;
    const bool w12 = dm < 12.0f;
    cnt[0] += (w3 && up)  ? 1.0f : 0.0f;
    cnt[1] += (w3 && dn)  ? 1.0f : 0.0f;
    cnt[2] += (w3 && lat) ? 1.0f : 0.0f;
    cnt[3] += (w5 && up)  ? 1.0f : 0.0f;
    cnt[4] += (w5 && dn)  ? 1.0f : 0.0f;
    cnt[5] += (w5 && lat) ? 1.0f : 0.0f;
    cnt[6] += (w8 && up)  ? 1.0f : 0.0f;
    cnt[7] += (w8 && dn)  ? 1.0f : 0.0f;
    cnt[8] += (w8 && lat) ? 1.0f : 0.0f;
    cnt[9]  += (w12 && up)  ? 1.0f : 0.0f;
    cnt[10] += (w12 && dn)  ? 1.0f : 0.0f;
    cnt[11] += (w12 && lat) ? 1.0f : 0.0f;

    dmin[0] = fminf(dmin[0], up  ? dm : LARGEV);
    dmin[1] = fminf(dmin[1], dn  ? dm : LARGEV);
    dmin[2] = fminf(dmin[2], lat ? dm : LARGEV);

    sumd += valid ? dist : 0.0f;
    vcnt += valid ? 1.0f : 0.0f;

    // octant sector (edges k*pi/4); angle==pi (dy==+0,dx<0) -> none; 0 -> s4
    int s;
    if (dy > 0.0f)      s = (dx > 0.0f) ? ((dy < dx) ? 4 : 5) : ((-dx < dy) ? 6 : 7);
    else if (dy < 0.0f) s = (dx < 0.0f) ? ((dx < dy) ? 0 : 1) : ((dx < -dy) ? 2 : 3);
    else                s = (dx > 0.0f) ? 4 : -1;
    if (!valid) s = -1;
#pragma unroll
    for (int k = 0; k < 8; ++k) {
      const bool in_s = (s == k);
      scnt[k] += in_s ? 1.0f : 0.0f;
      smin[k] = fminf(smin[k], in_s ? dm : LARGEV);
    }
  }

  // reduce 8 chunk partials (lanes differing in bits 0..2)
#pragma unroll
  for (int k = 0; k < 12; ++k) {
    cnt[k] += __shfl_xor(cnt[k], 1); cnt[k] += __shfl_xor(cnt[k], 2); cnt[k] += __shfl_xor(cnt[k], 4);
  }
#pragma unroll
  for (int k = 0; k < 8; ++k) {
    scnt[k] += __shfl_xor(scnt[k], 1); scnt[k] += __shfl_xor(scnt[k], 2); scnt[k] += __shfl_xor(scnt[k], 4);
  }
  sumd += __shfl_xor(sumd, 1); sumd += __shfl_xor(sumd, 2); sumd += __shfl_xor(sumd, 4);
  vcnt += __shfl_xor(vcnt, 1); vcnt += __shfl_xor(vcnt, 2); vcnt += __shfl_xor(vcnt, 4);
#pragma unroll
  for (int k = 0; k < 3; ++k) {
    dmin[k] = fminf(dmin[k], __shfl_xor(dmin[k], 1));
    dmin[k] = fminf(dmin[k], __shfl_xor(dmin[k], 2));
    dmin[k] = fminf(dmin[k], __shfl_xor(dmin[k], 4));
  }
#pragma unroll
  for (int k = 0; k < 8; ++k) {
    smin[k] = fminf(smin[k], __shfl_xor(smin[k], 1));
    smin[k] = fminf(smin[k], __shfl_xor(smin[k], 2));
    smin[k] = fminf(smin[k], __shfl_xor(smin[k], 4));
  }

  if (jc == 0) {
    float* f = feat + (size_t)(b * NPTS + i) * 33;
#pragma unroll
    for (int k = 0; k < 12; ++k) f[k] = cnt[k];
    f[12] = fminf(dmin[0] * 0.1f, 1.0f);
    f[13] = fminf(dmin[1] * 0.1f, 1.0f);
    f[14] = fminf(dmin[2] * 0.1f, 1.0f);
#pragma unroll
    for (int k = 0; k < 8; ++k) {
      f[15 + 2 * k] = scnt[k];
      f[16 + 2 * k] = fminf(smin[k] * 0.1f, 1.0f);
    }
    f[31] = cnt[9] + cnt[10] + cnt[11];
    f[32] = fminf(sumd / fmaxf(vcnt, 1.0f) * 0.1f, 1.0f);
  }
}

// ---------------------------------------------------------------------------
// MLP v2: grid 1024 blocks x 256 threads; each wave owns 8 rows.
// Per k-step: one W2 float2 load (global, L1-resident) feeds 16 FMAs
// (8 rows x 2 cols). g staged per-wave in LDS transposed [k][r] (stride 10,
// even -> float2 broadcast reads). x staged the same way. LN via shuffles.
// gT/xsT regions are per-wave -> no barrier inside the row-group pipeline.
// ---------------------------------------------------------------------------
#define RPW 8           // rows per wave
#define GSTR 10         // padded r-stride (even -> 8B-aligned float2 reads)

__global__ __launch_bounds__(256) void mlp_kernel(const float* __restrict__ feat,
    const float* __restrict__ W1, const float* __restrict__ b1,
    const float* __restrict__ gamma, const float* __restrict__ beta,
    const float* __restrict__ W2, const float* __restrict__ b2,
    float* __restrict__ out) {
  __shared__ float xsT[4][33][GSTR];    // [wave][k][r]  5280 B
  __shared__ float gT[4][128][GSTR];    // [wave][k][r] 20480 B
  const int tid = threadIdx.x;
  const int r0 = blockIdx.x * 32;       // 32 rows per block

  // stage feat transposed: xsT[w][k][r] = feat[r0 + w*8 + r][k]
  for (int idx = tid; idx < 32 * 33; idx += 256) {
    const int r = idx / 33;
    const int k = idx - r * 33;
    xsT[r >> 3][k][r & 7] = feat[(size_t)(r0 + r) * 33 + k];
  }
  __syncthreads();

  const int w = tid >> 6;
  const int l = tid & 63;
  const float2 b1v = ((const float2*)b1)[l];
  const float2 gav = ((const float2*)gamma)[l];
  const float2 bev = ((const float2*)beta)[l];
  const float2 b2v = ((const float2*)b2)[l];
  const float2* __restrict__ W1v = (const float2*)W1;
  const float2* __restrict__ W2v = (const float2*)W2;

  // ---- phase 1: h = x @ W1 + b1 for 8 rows at once ----
  float h0[RPW], h1[RPW];
#pragma unroll
  for (int r = 0; r < RPW; ++r) { h0[r] = b1v.x; h1[r] = b1v.y; }
  for (int k = 0; k < 33; ++k) {
    const float2 wv = W1v[k * 64 + l];
    const float2* xp = (const float2*)&xsT[w][k][0];
    const float2 x01 = xp[0], x23 = xp[1], x45 = xp[2], x67 = xp[3];
    const float xr[RPW] = {x01.x, x01.y, x23.x, x23.y, x45.x, x45.y, x67.x, x67.y};
#pragma unroll
    for (int r = 0; r < RPW; ++r) { h0[r] += xr[r] * wv.x; h1[r] += xr[r] * wv.y; }
  }

  // ---- phase 2: LayerNorm + exact GELU, write gT[w][k][r] ----
#pragma unroll
  for (int r = 0; r < RPW; ++r) {
    float s = h0[r] + h1[r];
#pragma unroll
    for (int o = 32; o > 0; o >>= 1) s += __shfl_xor(s, o);
    const float mu = s * 0.0078125f;
    const float d0 = h0[r] - mu, d1 = h1[r] - mu;
    float v = d0 * d0 + d1 * d1;
#pragma unroll
    for (int o = 32; o > 0; o >>= 1) v += __shfl_xor(v, o);
    const float inv = 1.0f / __fsqrt_rn(v * 0.0078125f + 1e-5f);
    float g0 = d0 * inv * gav.x + bev.x;
    float g1 = d1 * inv * gav.y + bev.y;
    g0 = 0.5f * g0 * (1.0f + erff(g0 * 0.70710678118654752f));
    g1 = 0.5f * g1 * (1.0f + erff(g1 * 0.70710678118654752f));
    gT[w][2 * l][r] = g0;
    gT[w][2 * l + 1][r] = g1;
  }
  // per-wave LDS region: in-wave RAW ordered by lgkmcnt (compiler-inserted)

  // ---- phase 3: out = g @ W2 + b2 for 8 rows at once ----
  float a0[RPW], a1[RPW];
#pragma unroll
  for (int r = 0; r < RPW; ++r) { a0[r] = b2v.x; a1[r] = b2v.y; }
#pragma unroll 4
  for (int k = 0; k < 128; ++k) {
    const float2 wv = W2v[k * 64 + l];
    const float2* gp = (const float2*)&gT[w][k][0];
    const float2 g01 = gp[0], g23 = gp[1], g45 = gp[2], g67 = gp[3];
    const float gr[RPW] = {g01.x, g01.y, g23.x, g23.y, g45.x, g45.y, g67.x, g67.y};
#pragma unroll
    for (int r = 0; r < RPW; ++r) { a0[r] += gr[r] * wv.x; a1[r] += gr[r] * wv.y; }
  }
#pragma unroll
  for (int r = 0; r < RPW; ++r) {
    const int row = r0 + w * RPW + r;
    ((float2*)out)[(size_t)row * 64 + l] = make_float2(a0[r], a1[r]);
  }
}

extern "C" void kernel_launch(void* const* d_in, const int* in_sizes, int n_in,
                              void* d_out, int out_size, void* d_ws, size_t ws_size,
                              hipStream_t stream) {
  const float* positions = (const float*)d_in[0];
  const void*  kpm_raw   = d_in[1];
  const float* W1    = (const float*)d_in[2];
  const float* b1    = (const float*)d_in[3];
  const float* gamma = (const float*)d_in[4];
  const float* beta  = (const float*)d_in[5];
  const float* W2    = (const float*)d_in[6];
  const float* b2    = (const float*)d_in[7];
  float* out = (float*)d_out;

  char* ws = (char*)d_ws;
  int* flag = (int*)ws;                                   // 4 B
  unsigned char* mask = (unsigned char*)(ws + 256);       // 32768 B
  float* feat = (float*)(ws + 256 + NROWS);               // 4.33 MB

  detect_kernel<<<1, 256, 0, stream>>>((const unsigned int*)kpm_raw, flag);
  decode_kernel<<<NROWS / 256, 256, 0, stream>>>(kpm_raw, flag, mask);
  feat_kernel<<<NBATCH * 16, 256, 0, stream>>>(positions, mask, feat);
  mlp_kernel<<<NROWS / 32, 256, 0, stream>>>(feat, W1, b1, gamma, beta, W2, b2, out);
}

// Round 3
// 174.901 us; speedup vs baseline: 1.6106x; 1.1912x over previous
//
#include <hip/hip_runtime.h>
#include <math.h>

#define NPTS 512
#define NBATCH 64
#define NROWS (NPTS * NBATCH)   // 32768
#define LARGEV 1000000.0f

__device__ __forceinline__ float rdlane(float v, int l) {
  return __uint_as_float((unsigned)__builtin_amdgcn_readlane((int)__float_as_uint(v), l));
}

// ---------------------------------------------------------------------------
// Mask dtype sniffer. flag bits: 1 = saw byte-pattern word>1, 2 = saw f32 1.0.
// decode: bit1 -> f32, else bit0 -> bytes, else i32. flag zeroed by memset.
// ---------------------------------------------------------------------------
__global__ __launch_bounds__(256) void detect_kernel(const unsigned int* __restrict__ raw,
                                                     int* __restrict__ flag) {
  __shared__ int s;
  if (threadIdx.x == 0) s = 0;
  __syncthreads();
  unsigned int w = raw[blockIdx.x * 256 + threadIdx.x];
  int f = (w == 0x3f800000u) ? 2 : ((w > 1u) ? 1 : 0);
  if (f) atomicOr(&s, f);
  __syncthreads();
  if (threadIdx.x == 0 && s) atomicOr(flag, s);
}

__global__ __launch_bounds__(256) void decode_kernel(const void* __restrict__ raw,
                                                     const int* __restrict__ flag,
                                                     unsigned char* __restrict__ mask) {
  int i = blockIdx.x * 256 + threadIdx.x;
  int f = flag[0];
  unsigned char m;
  if (f & 2)      m = (((const float*)raw)[i] != 0.0f) ? 1 : 0;
  else if (f & 1) m = ((const unsigned char*)raw)[i] ? 1 : 0;
  else            m = ((const int*)raw)[i] ? 1 : 0;
  mask[i] = m;
}

// ---------------------------------------------------------------------------
// Feature kernel v3: block = 16 rows x 16 j-chunks; grid 2048 (8 blocks/CU).
// 32 j-iters per lane; 4-step shfl_xor reduction over chunk lanes (bits 0..3).
// __f*_rn keeps dist bit-identical to numpy (threshold compares exact).
// ---------------------------------------------------------------------------
__global__ __launch_bounds__(256) void feat_kernel(const float* __restrict__ pos,
                                                   const unsigned char* __restrict__ mask,
                                                   float* __restrict__ feat) {
  __shared__ float2 sp[NPTS];
  __shared__ unsigned char smk[NPTS];
  const int b  = blockIdx.x >> 5;
  const int i0 = (blockIdx.x & 31) << 4;
  const int tid = threadIdx.x;
  for (int t = tid; t < NPTS; t += 256) {
    sp[t] = ((const float2*)pos)[b * NPTS + t];
    smk[t] = mask[b * NPTS + t];
  }
  __syncthreads();

  const int il = tid >> 4;       // row within block: 0..15
  const int jc = tid & 15;       // j-chunk: 0..15
  const int i  = i0 + il;
  const float2 pi = sp[i];

  float cnt[12];
#pragma unroll
  for (int k = 0; k < 12; ++k) cnt[k] = 0.0f;
  float dmin[3] = {LARGEV, LARGEV, LARGEV};
  float scnt[8], smin[8];
#pragma unroll
  for (int k = 0; k < 8; ++k) { scnt[k] = 0.0f; smin[k] = LARGEV; }
  float sumd = 0.0f, vcnt = 0.0f;

  for (int jj = 0; jj < 32; ++jj) {
    const int j = (jj << 4) + jc;
    const bool valid = (j != i) && (smk[j] == 0);
    const float2 pj = sp[j];
    const float dx = __fsub_rn(pj.x, pi.x);
    const float dy = __fsub_rn(pj.y, pi.y);
    const float d2 = __fadd_rn(__fadd_rn(__fmul_rn(dx, dx), __fmul_rn(dy, dy)), 1e-8f);
    const float dist = __fsqrt_rn(d2);
    const float dm = valid ? dist : LARGEV;
    const float ady = fabsf(dy);
    const bool up = dx >  __fmul_rn(ady, 0.5f);
    const bool dn = dx < -__fmul_rn(ady, 0.5f);
    const bool lat = !up && !dn;

    const bool w3  = dm <  3.0f;
    const bool w5  = dm <  5.0f;
    const bool w8  = dm <  8.0f;
    const bool w12 = dm < 12.0f;
    cnt[0] += (w3 && up)  ? 1.0f : 0.0f;
    cnt[1] += (w3 && dn)  ? 1.0f : 0.0f;
    cnt[2] += (w3 && lat) ? 1.0f : 0.0f;
    cnt[3] += (w5 && up)  ? 1.0f : 0.0f;
    cnt[4] += (w5 && dn)  ? 1.0f : 0.0f;
    cnt[5] += (w5 && lat) ? 1.0f : 0.0f;
    cnt[6] += (w8 && up)  ? 1.0f : 0.0f;
    cnt[7] += (w8 && dn)  ? 1.0f : 0.0f;
    cnt[8] += (w8 && lat) ? 1.0f : 0.0f;
    cnt[9]  += (w12 && up)  ? 1.0f : 0.0f;
    cnt[10] += (w12 && dn)  ? 1.0f : 0.0f;
    cnt[11] += (w12 && lat) ? 1.0f : 0.0f;

    dmin[0] = fminf(dmin[0], up  ? dm : LARGEV);
    dmin[1] = fminf(dmin[1], dn  ? dm : LARGEV);
    dmin[2] = fminf(dmin[2], lat ? dm : LARGEV);

    sumd += valid ? dist : 0.0f;
    vcnt += valid ? 1.0f : 0.0f;

    // octant sector (edges k*pi/4); angle==pi (dy==+0,dx<0) -> none; 0 -> s4
    int s;
    if (dy > 0.0f)      s = (dx > 0.0f) ? ((dy < dx) ? 4 : 5) : ((-dx < dy) ? 6 : 7);
    else if (dy < 0.0f) s = (dx < 0.0f) ? ((dx < dy) ? 0 : 1) : ((dx < -dy) ? 2 : 3);
    else                s = (dx > 0.0f) ? 4 : -1;
    if (!valid) s = -1;
#pragma unroll
    for (int k = 0; k < 8; ++k) {
      const bool in_s = (s == k);
      scnt[k] += in_s ? 1.0f : 0.0f;
      smin[k] = fminf(smin[k], in_s ? dm : LARGEV);
    }
  }

  // reduce 16 chunk partials (lanes differing in bits 0..3)
#pragma unroll
  for (int k = 0; k < 12; ++k) {
    cnt[k] += __shfl_xor(cnt[k], 1); cnt[k] += __shfl_xor(cnt[k], 2);
    cnt[k] += __shfl_xor(cnt[k], 4); cnt[k] += __shfl_xor(cnt[k], 8);
  }
#pragma unroll
  for (int k = 0; k < 8; ++k) {
    scnt[k] += __shfl_xor(scnt[k], 1); scnt[k] += __shfl_xor(scnt[k], 2);
    scnt[k] += __shfl_xor(scnt[k], 4); scnt[k] += __shfl_xor(scnt[k], 8);
  }
  sumd += __shfl_xor(sumd, 1); sumd += __shfl_xor(sumd, 2);
  sumd += __shfl_xor(sumd, 4); sumd += __shfl_xor(sumd, 8);
  vcnt += __shfl_xor(vcnt, 1); vcnt += __shfl_xor(vcnt, 2);
  vcnt += __shfl_xor(vcnt, 4); vcnt += __shfl_xor(vcnt, 8);
#pragma unroll
  for (int k = 0; k < 3; ++k) {
    dmin[k] = fminf(dmin[k], __shfl_xor(dmin[k], 1));
    dmin[k] = fminf(dmin[k], __shfl_xor(dmin[k], 2));
    dmin[k] = fminf(dmin[k], __shfl_xor(dmin[k], 4));
    dmin[k] = fminf(dmin[k], __shfl_xor(dmin[k], 8));
  }
#pragma unroll
  for (int k = 0; k < 8; ++k) {
    smin[k] = fminf(smin[k], __shfl_xor(smin[k], 1));
    smin[k] = fminf(smin[k], __shfl_xor(smin[k], 2));
    smin[k] = fminf(smin[k], __shfl_xor(smin[k], 4));
    smin[k] = fminf(smin[k], __shfl_xor(smin[k], 8));
  }

  if (jc == 0) {
    float* f = feat + (size_t)(b * NPTS + i) * 33;
#pragma unroll
    for (int k = 0; k < 12; ++k) f[k] = cnt[k];
    f[12] = fminf(dmin[0] * 0.1f, 1.0f);
    f[13] = fminf(dmin[1] * 0.1f, 1.0f);
    f[14] = fminf(dmin[2] * 0.1f, 1.0f);
#pragma unroll
    for (int k = 0; k < 8; ++k) {
      f[15 + 2 * k] = scnt[k];
      f[16 + 2 * k] = fminf(smin[k] * 0.1f, 1.0f);
    }
    f[31] = cnt[9] + cnt[10] + cnt[11];
    f[32] = fminf(sumd / fmaxf(vcnt, 1.0f) * 0.1f, 1.0f);
  }
}

// ---------------------------------------------------------------------------
// MLP v3: ZERO LDS, zero barriers. Wave owns 8 rows; lane owns cols 2l,2l+1.
// Row-broadcast values come from v_readlane (g[row][k] lives in lane k>>1,
// component k&1) -> SGPR operand folds straight into v_fmac. x staged in 5
// VGPRs/lane via one coalesced load of the wave's 264 contiguous floats.
// __launch_bounds__(256,4) caps VGPR at 128 (4 waves/SIMD).
// ---------------------------------------------------------------------------
#define RPW 8

__global__ __launch_bounds__(256, 4) void mlp_kernel(const float* __restrict__ feat,
    const float* __restrict__ W1, const float* __restrict__ b1,
    const float* __restrict__ gamma, const float* __restrict__ beta,
    const float* __restrict__ W2, const float* __restrict__ b2,
    float* __restrict__ out) {
  const int tid = threadIdx.x;
  const int w = tid >> 6;
  const int l = tid & 63;
  const int r0w = blockIdx.x * 32 + w * RPW;   // first of this wave's 8 rows

  // x stage: 264 contiguous floats -> 5 regs/lane (coalesced)
  const float* __restrict__ xf = feat + (size_t)r0w * 33;
  float xreg[5];
#pragma unroll
  for (int c = 0; c < 4; ++c) xreg[c] = xf[c * 64 + l];
  xreg[4] = (l < 8) ? xf[256 + l] : 0.0f;

  const float2 b1v = ((const float2*)b1)[l];
  const float2 gav = ((const float2*)gamma)[l];
  const float2 bev = ((const float2*)beta)[l];
  const float2 b2v = ((const float2*)b2)[l];
  const float2* __restrict__ W1v = (const float2*)W1;
  const float2* __restrict__ W2v = (const float2*)W2;

  // ---- phase 1: h = x @ W1 + b1 (readlane broadcast of x) ----
  float h0[RPW], h1[RPW];
#pragma unroll
  for (int r = 0; r < RPW; ++r) { h0[r] = b1v.x; h1[r] = b1v.y; }
#pragma unroll
  for (int k = 0; k < 33; ++k) {
    const float2 wv = W1v[k * 64 + l];
#pragma unroll
    for (int r = 0; r < RPW; ++r) {
      const int v = r * 33 + k;                 // compile-time
      const float xv = rdlane(xreg[v >> 6], v & 63);
      h0[r] += xv * wv.x;
      h1[r] += xv * wv.y;
    }
  }

  // ---- phase 2: LayerNorm + exact GELU (in registers) ----
  float g0[RPW], g1[RPW];
#pragma unroll
  for (int r = 0; r < RPW; ++r) {
    float s = h0[r] + h1[r];
#pragma unroll
    for (int o = 32; o > 0; o >>= 1) s += __shfl_xor(s, o);
    const float mu = s * 0.0078125f;
    const float d0 = h0[r] - mu, d1 = h1[r] - mu;
    float v = d0 * d0 + d1 * d1;
#pragma unroll
    for (int o = 32; o > 0; o >>= 1) v += __shfl_xor(v, o);
    const float inv = 1.0f / __fsqrt_rn(v * 0.0078125f + 1e-5f);
    float a = d0 * inv * gav.x + bev.x;
    float b = d1 * inv * gav.y + bev.y;
    g0[r] = 0.5f * a * (1.0f + erff(a * 0.70710678118654752f));
    g1[r] = 0.5f * b * (1.0f + erff(b * 0.70710678118654752f));
  }

  // ---- phase 3: out = g @ W2 + b2 (readlane broadcast of g) ----
  float a0[RPW], a1[RPW];
#pragma unroll
  for (int r = 0; r < RPW; ++r) { a0[r] = b2v.x; a1[r] = b2v.y; }
#pragma unroll 8
  for (int kp = 0; kp < 64; ++kp) {            // k = 2*kp (even), 2*kp+1 (odd)
    const float2 wva = W2v[(2 * kp) * 64 + l];
    const float2 wvb = W2v[(2 * kp + 1) * 64 + l];
#pragma unroll
    for (int r = 0; r < RPW; ++r) {
      const float ga = rdlane(g0[r], kp);      // col 2*kp of row r
      const float gb = rdlane(g1[r], kp);      // col 2*kp+1 of row r
      a0[r] += ga * wva.x; a1[r] += ga * wva.y;
      a0[r] += gb * wvb.x; a1[r] += gb * wvb.y;
    }
  }
#pragma unroll
  for (int r = 0; r < RPW; ++r) {
    ((float2*)out)[(size_t)(r0w + r) * 64 + l] = make_float2(a0[r], a1[r]);
  }
}

extern "C" void kernel_launch(void* const* d_in, const int* in_sizes, int n_in,
                              void* d_out, int out_size, void* d_ws, size_t ws_size,
                              hipStream_t stream) {
  const float* positions = (const float*)d_in[0];
  const void*  kpm_raw   = d_in[1];
  const float* W1    = (const float*)d_in[2];
  const float* b1    = (const float*)d_in[3];
  const float* gamma = (const float*)d_in[4];
  const float* beta  = (const float*)d_in[5];
  const float* W2    = (const float*)d_in[6];
  const float* b2    = (const float*)d_in[7];
  float* out = (float*)d_out;

  char* ws = (char*)d_ws;
  int* flag = (int*)ws;                                   // 4 B
  unsigned char* mask = (unsigned char*)(ws + 256);       // 32768 B
  float* feat = (float*)(ws + 256 + NROWS);               // 4.33 MB

  hipMemsetAsync(flag, 0, sizeof(int), stream);
  detect_kernel<<<NROWS / 4 / 256, 256, 0, stream>>>((const unsigned int*)kpm_raw, flag);
  decode_kernel<<<NROWS / 256, 256, 0, stream>>>(kpm_raw, flag, mask);
  feat_kernel<<<NBATCH * 32, 256, 0, stream>>>(positions, mask, feat);
  mlp_kernel<<<NROWS / 32, 256, 0, stream>>>(feat, W1, b1, gamma, beta, W2, b2, out);
}

// Round 4
// 150.056 us; speedup vs baseline: 1.8772x; 1.1656x over previous
//
#include <hip/hip_runtime.h>
#include <math.h>

#define NPTS 512
#define NBATCH 64
#define NROWS (NPTS * NBATCH)   // 32768
#define LARGEV 1000000.0f

__device__ __forceinline__ float rdlane(float v, int l) {
  return __uint_as_float((unsigned)__builtin_amdgcn_readlane((int)__float_as_uint(v), l));
}

// ---------------------------------------------------------------------------
// Feature kernel v4: fused mask-dtype sniff + decode + pairwise features.
// Block = 16 rows x 16 j-chunks; grid 2048.
// - masked j positions staged as NaN: kills threshold/dir/sector compares and
//   fminf (minNum) drops NaN -> no per-iter mask load or valid-select.
// - anchor pi read from GLOBAL (masked rows still get real features).
// - 12 threshold-dir counts packed as 3 u32 (byte/threshold, reg/direction);
//   nested thresholds -> single cndmask-chain addend.
// - sector count+min via per-lane LDS uint2 RMW (slot 8 = trash for
//   invalid/self/angle==pi): moves a 40-op VALU scatter onto the LDS pipe.
// - __f*_rn keeps dist bit-identical to numpy (threshold compares exact).
// ---------------------------------------------------------------------------
__global__ __launch_bounds__(256) void feat_kernel(const float* __restrict__ pos,
                                                   const void* __restrict__ kpm,
                                                   float* __restrict__ feat) {
  __shared__ float2 sp[NPTS];
  __shared__ uint2 scr[256 * 9];     // [lane][slot] = {min_bits, count}
  __shared__ int sflag;
  const int b  = blockIdx.x >> 5;
  const int i0 = (blockIdx.x & 31) << 4;
  const int tid = threadIdx.x;

  // ---- inline dtype sniff over first 2KB of the raw mask buffer ----
  if (tid == 0) sflag = 0;
  __syncthreads();
  {
    const unsigned int* rw = (const unsigned int*)kpm;
    const unsigned int w0 = rw[tid];          // words 0..255
    const unsigned int w1 = rw[tid + 256];    // words 256..511 (within 32KB min)
    int f = 0;
    if (w0 == 0x3f800000u || w1 == 0x3f800000u) f |= 2;   // float 1.0 pattern
    if (w0 > 1u || w1 > 1u) f |= 1;                        // packed-byte pattern
    if (f) atomicOr(&sflag, f);
  }
  __syncthreads();
  const int fmt = sflag;   // 2=>f32, 1=>bytes, 0=>i32 (f32 priority)

  // ---- stage positions, NaN-ifying masked points ----
  for (int t = tid; t < NPTS; t += 256) {
    bool m;
    if (fmt & 2)      m = ((const float*)kpm)[b * NPTS + t] != 0.0f;
    else if (fmt & 1) m = ((const unsigned char*)kpm)[b * NPTS + t] != 0;
    else              m = ((const int*)kpm)[b * NPTS + t] != 0;
    float2 p = ((const float2*)pos)[b * NPTS + t];
    if (m) { p.x = __builtin_nanf(""); p.y = p.x; }
    sp[t] = p;
  }
  // per-lane scratch init (no barrier needed: slots are private to the lane)
  uint2* __restrict__ myscr = &scr[tid * 9];
#pragma unroll
  for (int k = 0; k < 9; ++k) myscr[k] = make_uint2(__float_as_uint(LARGEV), 0u);
  __syncthreads();

  const int il = tid >> 4;       // row within block: 0..15
  const int jc = tid & 15;       // j-chunk: 0..15
  const int i  = i0 + il;
  const float2 pi = ((const float2*)pos)[b * NPTS + i];   // real anchor (global)

  unsigned cu = 0u, cd = 0u, cl = 0u;   // packed counts: byte0=w3..byte3=w12
  float dmin0 = LARGEV, dmin1 = LARGEV, dmin2 = LARGEV;
  float sumd = 0.0f;
  int vcn = 0;

#pragma unroll 4
  for (int jj = 0; jj < 32; ++jj) {
    const int j = (jj << 4) + jc;
    const float2 pj = sp[j];
    const float dx = __fsub_rn(pj.x, pi.x);
    const float dy = __fsub_rn(pj.y, pi.y);
    const float d2 = __fadd_rn(__fadd_rn(__fmul_rn(dx, dx), __fmul_rn(dy, dy)), 1e-8f);
    float dist = __fsqrt_rn(d2);
    dist = (j == i) ? __builtin_nanf("") : dist;          // self -> NaN

    const float hdy = __fmul_rn(fabsf(dy), 0.5f);
    const bool up = dx > hdy;
    const bool dn = dx < -hdy;

    const bool w3  = dist <  3.0f;
    const bool w5  = dist <  5.0f;
    const bool w8  = dist <  8.0f;
    const bool w12 = dist < 12.0f;
    const unsigned a = w3 ? 0x01010101u
                     : (w5 ? 0x01010100u
                     : (w8 ? 0x01010000u
                     : (w12 ? 0x01000000u : 0u)));
    cu += up ? a : 0u;
    cd += dn ? a : 0u;
    cl += (!up && !dn) ? a : 0u;

    dmin0 = fminf(dmin0, up ? dist : LARGEV);              // up false for NaN
    dmin1 = fminf(dmin1, dn ? dist : LARGEV);
    dmin2 = fminf(dmin2, (!up && !dn) ? dist : LARGEV);    // NaN dropped (minNum)

    const bool c = dist < 1.0e30f;                         // "valid" (NaN false)
    sumd += c ? dist : 0.0f;
    vcn  += c ? 1 : 0;

    // octant sector; dy==0,dx>0 -> s4 (angle 0); dy==0,dx<=0 / NaN / self -> 8
    const int slot = (dy > 0.0f)
        ? ((dx > 0.0f) ? ((dy < dx) ? 4 : 5) : ((-dx < dy) ? 6 : 7))
        : ((dy < 0.0f) ? ((dx < 0.0f) ? ((dx < dy) ? 0 : 1) : ((dx < -dy) ? 2 : 3))
                       : ((dx > 0.0f) ? 4 : 8));
    uint2 v = myscr[slot];
    v.x = __float_as_uint(fminf(__uint_as_float(v.x), dist));  // NaN dropped
    v.y += 1u;
    myscr[slot] = v;
  }

  // ---- unpack packed counts ----
  float cnt[12];
  cnt[0] = (float)(cu & 0xffu);  cnt[3] = (float)((cu >> 8) & 0xffu);
  cnt[6] = (float)((cu >> 16) & 0xffu);  cnt[9]  = (float)(cu >> 24);
  cnt[1] = (float)(cd & 0xffu);  cnt[4] = (float)((cd >> 8) & 0xffu);
  cnt[7] = (float)((cd >> 16) & 0xffu);  cnt[10] = (float)(cd >> 24);
  cnt[2] = (float)(cl & 0xffu);  cnt[5] = (float)((cl >> 8) & 0xffu);
  cnt[8] = (float)((cl >> 16) & 0xffu);  cnt[11] = (float)(cl >> 24);
  float scnt[8], smin[8];
#pragma unroll
  for (int k = 0; k < 8; ++k) {
    const uint2 v = myscr[k];
    scnt[k] = (float)v.y;
    smin[k] = __uint_as_float(v.x);
  }
  float vcnt = (float)vcn;
  float dmin[3] = {dmin0, dmin1, dmin2};

  // ---- reduce 16 chunk partials (lanes differing in bits 0..3) ----
#pragma unroll
  for (int k = 0; k < 12; ++k) {
    cnt[k] += __shfl_xor(cnt[k], 1); cnt[k] += __shfl_xor(cnt[k], 2);
    cnt[k] += __shfl_xor(cnt[k], 4); cnt[k] += __shfl_xor(cnt[k], 8);
  }
#pragma unroll
  for (int k = 0; k < 8; ++k) {
    scnt[k] += __shfl_xor(scnt[k], 1); scnt[k] += __shfl_xor(scnt[k], 2);
    scnt[k] += __shfl_xor(scnt[k], 4); scnt[k] += __shfl_xor(scnt[k], 8);
  }
  sumd += __shfl_xor(sumd, 1); sumd += __shfl_xor(sumd, 2);
  sumd += __shfl_xor(sumd, 4); sumd += __shfl_xor(sumd, 8);
  vcnt += __shfl_xor(vcnt, 1); vcnt += __shfl_xor(vcnt, 2);
  vcnt += __shfl_xor(vcnt, 4); vcnt += __shfl_xor(vcnt, 8);
#pragma unroll
  for (int k = 0; k < 3; ++k) {
    dmin[k] = fminf(dmin[k], __shfl_xor(dmin[k], 1));
    dmin[k] = fminf(dmin[k], __shfl_xor(dmin[k], 2));
    dmin[k] = fminf(dmin[k], __shfl_xor(dmin[k], 4));
    dmin[k] = fminf(dmin[k], __shfl_xor(dmin[k], 8));
  }
#pragma unroll
  for (int k = 0; k < 8; ++k) {
    smin[k] = fminf(smin[k], __shfl_xor(smin[k], 1));
    smin[k] = fminf(smin[k], __shfl_xor(smin[k], 2));
    smin[k] = fminf(smin[k], __shfl_xor(smin[k], 4));
    smin[k] = fminf(smin[k], __shfl_xor(smin[k], 8));
  }

  if (jc == 0) {
    float* f = feat + (size_t)(b * NPTS + i) * 33;
#pragma unroll
    for (int k = 0; k < 12; ++k) f[k] = cnt[k];
    f[12] = fminf(dmin[0] * 0.1f, 1.0f);
    f[13] = fminf(dmin[1] * 0.1f, 1.0f);
    f[14] = fminf(dmin[2] * 0.1f, 1.0f);
#pragma unroll
    for (int k = 0; k < 8; ++k) {
      f[15 + 2 * k] = scnt[k];
      f[16 + 2 * k] = fminf(smin[k] * 0.1f, 1.0f);
    }
    f[31] = cnt[9] + cnt[10] + cnt[11];
    f[32] = fminf(sumd / fmaxf(vcnt, 1.0f) * 0.1f, 1.0f);
  }
}

// ---------------------------------------------------------------------------
// MLP v3 (unchanged): ZERO LDS, zero barriers. Wave owns 8 rows; lane owns
// cols 2l,2l+1. Row-broadcasts via v_readlane -> SGPR operand folds into
// v_fmac. __launch_bounds__(256,4) caps VGPR at 128.
// ---------------------------------------------------------------------------
#define RPW 8

__global__ __launch_bounds__(256, 4) void mlp_kernel(const float* __restrict__ feat,
    const float* __restrict__ W1, const float* __restrict__ b1,
    const float* __restrict__ gamma, const float* __restrict__ beta,
    const float* __restrict__ W2, const float* __restrict__ b2,
    float* __restrict__ out) {
  const int tid = threadIdx.x;
  const int w = tid >> 6;
  const int l = tid & 63;
  const int r0w = blockIdx.x * 32 + w * RPW;   // first of this wave's 8 rows

  // x stage: 264 contiguous floats -> 5 regs/lane (coalesced)
  const float* __restrict__ xf = feat + (size_t)r0w * 33;
  float xreg[5];
#pragma unroll
  for (int c = 0; c < 4; ++c) xreg[c] = xf[c * 64 + l];
  xreg[4] = (l < 8) ? xf[256 + l] : 0.0f;

  const float2 b1v = ((const float2*)b1)[l];
  const float2 gav = ((const float2*)gamma)[l];
  const float2 bev = ((const float2*)beta)[l];
  const float2 b2v = ((const float2*)b2)[l];
  const float2* __restrict__ W1v = (const float2*)W1;
  const float2* __restrict__ W2v = (const float2*)W2;

  // ---- phase 1: h = x @ W1 + b1 (readlane broadcast of x) ----
  float h0[RPW], h1[RPW];
#pragma unroll
  for (int r = 0; r < RPW; ++r) { h0[r] = b1v.x; h1[r] = b1v.y; }
#pragma unroll
  for (int k = 0; k < 33; ++k) {
    const float2 wv = W1v[k * 64 + l];
#pragma unroll
    for (int r = 0; r < RPW; ++r) {
      const int v = r * 33 + k;                 // compile-time
      const float xv = rdlane(xreg[v >> 6], v & 63);
      h0[r] += xv * wv.x;
      h1[r] += xv * wv.y;
    }
  }

  // ---- phase 2: LayerNorm + exact GELU (in registers) ----
  float g0[RPW], g1[RPW];
#pragma unroll
  for (int r = 0; r < RPW; ++r) {
    float s = h0[r] + h1[r];
#pragma unroll
    for (int o = 32; o > 0; o >>= 1) s += __shfl_xor(s, o);
    const float mu = s * 0.0078125f;
    const float d0 = h0[r] - mu, d1 = h1[r] - mu;
    float v = d0 * d0 + d1 * d1;
#pragma unroll
    for (int o = 32; o > 0; o >>= 1) v += __shfl_xor(v, o);
    const float inv = 1.0f / __fsqrt_rn(v * 0.0078125f + 1e-5f);
    float a = d0 * inv * gav.x + bev.x;
    float b = d1 * inv * gav.y + bev.y;
    g0[r] = 0.5f * a * (1.0f + erff(a * 0.70710678118654752f));
    g1[r] = 0.5f * b * (1.0f + erff(b * 0.70710678118654752f));
  }

  // ---- phase 3: out = g @ W2 + b2 (readlane broadcast of g) ----
  float a0[RPW], a1[RPW];
#pragma unroll
  for (int r = 0; r < RPW; ++r) { a0[r] = b2v.x; a1[r] = b2v.y; }
#pragma unroll 8
  for (int kp = 0; kp < 64; ++kp) {            // k = 2*kp (even), 2*kp+1 (odd)
    const float2 wva = W2v[(2 * kp) * 64 + l];
    const float2 wvb = W2v[(2 * kp + 1) * 64 + l];
#pragma unroll
    for (int r = 0; r < RPW; ++r) {
      const float ga = rdlane(g0[r], kp);      // col 2*kp of row r
      const float gb = rdlane(g1[r], kp);      // col 2*kp+1 of row r
      a0[r] += ga * wva.x; a1[r] += ga * wva.y;
      a0[r] += gb * wvb.x; a1[r] += gb * wvb.y;
    }
  }
#pragma unroll
  for (int r = 0; r < RPW; ++r) {
    ((float2*)out)[(size_t)(r0w + r) * 64 + l] = make_float2(a0[r], a1[r]);
  }
}

extern "C" void kernel_launch(void* const* d_in, const int* in_sizes, int n_in,
                              void* d_out, int out_size, void* d_ws, size_t ws_size,
                              hipStream_t stream) {
  const float* positions = (const float*)d_in[0];
  const void*  kpm_raw   = d_in[1];
  const float* W1    = (const float*)d_in[2];
  const float* b1    = (const float*)d_in[3];
  const float* gamma = (const float*)d_in[4];
  const float* beta  = (const float*)d_in[5];
  const float* W2    = (const float*)d_in[6];
  const float* b2    = (const float*)d_in[7];
  float* out = (float*)d_out;

  float* feat = (float*)d_ws;   // 32768*33*4 = 4.33 MB

  feat_kernel<<<NBATCH * 32, 256, 0, stream>>>(positions, kpm_raw, feat);
  mlp_kernel<<<NROWS / 32, 256, 0, stream>>>(feat, W1, b1, gamma, beta, W2, b2, out);
}

// Round 6
// 144.727 us; speedup vs baseline: 1.9463x; 1.0368x over previous
//
#include <hip/hip_runtime.h>
#include <math.h>

#define NPTS 512
#define NBATCH 64
#define NROWS (NPTS * NBATCH)   // 32768
#define LARGEV 1000000.0f
#define RPW 8                   // rows per wave in the MLP phases

typedef float v2f __attribute__((ext_vector_type(2)));

__device__ __forceinline__ float rdlane(float v, int l) {
  return __uint_as_float((unsigned)__builtin_amdgcn_readlane((int)__float_as_uint(v), l));
}

// acc = s*w + acc on both components. LLVM selects v_pk_fma_f32 (VOP3P) for
// llvm.fma.v2f32 on gfx950 when it can; falls back to 2x v_fma_f32 otherwise.
// (Round-5 lesson: VOP3P sources are 64-bit pairs -- a raw "s"(float) inline
// asm operand is an invalid 32-bit operand. Let ISel pick the encoding.)
__device__ __forceinline__ void pk_fma(v2f& acc, float s, v2f w) {
  acc = __builtin_elementwise_fma(w, (v2f){s, s}, acc);
}

// ---------------------------------------------------------------------------
// Fully fused kernel: mask sniff + decode + pairwise features + MLP.
// Block = 256 threads = 32 rows x 8 j-chunks (feat) = 4 waves x 8 rows (MLP).
// Grid 1024 (4 blocks/CU; LDS 26.8KB).
//
// Feature section (identical arithmetic to round-4 v4):
// - masked j staged as NaN (kills compares; fminf drops NaN); anchor from
//   global (masked rows still get real features); self -> NaN.
// - nested thresholds -> 3 packed u32 counters (byte per threshold).
// - sector count+min via per-lane LDS uint2 RMW (slot 8 = trash).
// - __f*_rn keeps dist bit-identical to numpy.
//
// Handoff: row il's 33 feats (held by reducer lane il*8) go to LDS
// xs[il][0..32]. Rows 8w..8w+7 are written by lanes 64w+8r -- the SAME wave
// that consumes them in the MLP -> no barrier needed (in-wave DS ops execute
// in issue order; compiler inserts lgkmcnt waits for the aliasing reads).
// Proven pattern: rounds 1-3 mlp hs[] handoff.
//
// MLP section (round-3 arithmetic + v2f packing): zero barriers, readlane
// broadcasts, lane owns cols (2l,2l+1), wave owns 8 rows.
// ---------------------------------------------------------------------------
__global__ __launch_bounds__(256, 4) void fused_kernel(const float* __restrict__ pos,
    const void* __restrict__ kpm,
    const float* __restrict__ W1, const float* __restrict__ b1,
    const float* __restrict__ gamma, const float* __restrict__ beta,
    const float* __restrict__ W2, const float* __restrict__ b2,
    float* __restrict__ out) {
  __shared__ float2 sp[NPTS];        //  4096 B
  __shared__ uint2 scr[256 * 9];     // 18432 B  [lane][slot] = {min_bits, count}
  __shared__ float xs[32 * 33];      //  4224 B  per-row feature vectors
  __shared__ int sflag;
  const int b  = blockIdx.x >> 4;
  const int i0 = (blockIdx.x & 15) << 5;
  const int tid = threadIdx.x;

  // ---- inline mask-dtype sniff over first 2KB of the raw mask buffer ----
  if (tid == 0) sflag = 0;
  __syncthreads();
  {
    const unsigned int* rw = (const unsigned int*)kpm;
    const unsigned int w0 = rw[tid];
    const unsigned int w1 = rw[tid + 256];
    int f = 0;
    if (w0 == 0x3f800000u || w1 == 0x3f800000u) f |= 2;   // float 1.0 pattern
    if (w0 > 1u || w1 > 1u) f |= 1;                        // packed-byte pattern
    if (f) atomicOr(&sflag, f);
  }
  __syncthreads();
  const int fmt = sflag;   // 2=>f32, 1=>bytes, 0=>i32 (f32 priority)

  // ---- stage positions, NaN-ifying masked points ----
  for (int t = tid; t < NPTS; t += 256) {
    bool m;
    if (fmt & 2)      m = ((const float*)kpm)[b * NPTS + t] != 0.0f;
    else if (fmt & 1) m = ((const unsigned char*)kpm)[b * NPTS + t] != 0;
    else              m = ((const int*)kpm)[b * NPTS + t] != 0;
    float2 p = ((const float2*)pos)[b * NPTS + t];
    if (m) { p.x = __builtin_nanf(""); p.y = p.x; }
    sp[t] = p;
  }
  uint2* __restrict__ myscr = &scr[tid * 9];
#pragma unroll
  for (int k = 0; k < 9; ++k) myscr[k] = make_uint2(__float_as_uint(LARGEV), 0u);
  __syncthreads();

  const int il = tid >> 3;       // row within block: 0..31
  const int jc = tid & 7;        // j-chunk: 0..7
  const int i  = i0 + il;
  const float2 pi = ((const float2*)pos)[b * NPTS + i];   // real anchor (global)

  unsigned cu = 0u, cd = 0u, cl = 0u;   // packed counts: byte0=w3..byte3=w12
  float dmin0 = LARGEV, dmin1 = LARGEV, dmin2 = LARGEV;
  float sumd = 0.0f;
  int vcn = 0;

#pragma unroll 4
  for (int jj = 0; jj < 64; ++jj) {
    const int j = (jj << 3) + jc;
    const float2 pj = sp[j];
    const float dx = __fsub_rn(pj.x, pi.x);
    const float dy = __fsub_rn(pj.y, pi.y);
    const float d2 = __fadd_rn(__fadd_rn(__fmul_rn(dx, dx), __fmul_rn(dy, dy)), 1e-8f);
    float dist = __fsqrt_rn(d2);
    dist = (j == i) ? __builtin_nanf("") : dist;          // self -> NaN

    const float hdy = __fmul_rn(fabsf(dy), 0.5f);
    const bool up = dx > hdy;
    const bool dn = dx < -hdy;

    const bool w3  = dist <  3.0f;
    const bool w5  = dist <  5.0f;
    const bool w8  = dist <  8.0f;
    const bool w12 = dist < 12.0f;
    const unsigned a = w3 ? 0x01010101u
                     : (w5 ? 0x01010100u
                     : (w8 ? 0x01010000u
                     : (w12 ? 0x01000000u : 0u)));
    cu += up ? a : 0u;
    cd += dn ? a : 0u;
    cl += (!up && !dn) ? a : 0u;

    dmin0 = fminf(dmin0, up ? dist : LARGEV);
    dmin1 = fminf(dmin1, dn ? dist : LARGEV);
    dmin2 = fminf(dmin2, (!up && !dn) ? dist : LARGEV);   // NaN dropped (minNum)

    const bool c = dist < 1.0e30f;                         // NaN -> false
    sumd += c ? dist : 0.0f;
    vcn  += c ? 1 : 0;

    // octant sector; dy==0,dx>0 -> s4 (angle 0); dy==0,dx<=0 / NaN -> 8
    const int slot = (dy > 0.0f)
        ? ((dx > 0.0f) ? ((dy < dx) ? 4 : 5) : ((-dx < dy) ? 6 : 7))
        : ((dy < 0.0f) ? ((dx < 0.0f) ? ((dx < dy) ? 0 : 1) : ((dx < -dy) ? 2 : 3))
                       : ((dx > 0.0f) ? 4 : 8));
    uint2 v = myscr[slot];
    v.x = __float_as_uint(fminf(__uint_as_float(v.x), dist));
    v.y += 1u;
    myscr[slot] = v;
  }

  // ---- unpack + reduce 8 chunk partials (lanes differing in bits 0..2) ----
  float cnt[12];
  cnt[0] = (float)(cu & 0xffu);  cnt[3] = (float)((cu >> 8) & 0xffu);
  cnt[6] = (float)((cu >> 16) & 0xffu);  cnt[9]  = (float)(cu >> 24);
  cnt[1] = (float)(cd & 0xffu);  cnt[4] = (float)((cd >> 8) & 0xffu);
  cnt[7] = (float)((cd >> 16) & 0xffu);  cnt[10] = (float)(cd >> 24);
  cnt[2] = (float)(cl & 0xffu);  cnt[5] = (float)((cl >> 8) & 0xffu);
  cnt[8] = (float)((cl >> 16) & 0xffu);  cnt[11] = (float)(cl >> 24);
  float scnt[8], smin[8];
#pragma unroll
  for (int k = 0; k < 8; ++k) {
    const uint2 v = myscr[k];
    scnt[k] = (float)v.y;
    smin[k] = __uint_as_float(v.x);
  }
  float vcnt = (float)vcn;
  float dmin[3] = {dmin0, dmin1, dmin2};

#pragma unroll
  for (int k = 0; k < 12; ++k) {
    cnt[k] += __shfl_xor(cnt[k], 1); cnt[k] += __shfl_xor(cnt[k], 2); cnt[k] += __shfl_xor(cnt[k], 4);
  }
#pragma unroll
  for (int k = 0; k < 8; ++k) {
    scnt[k] += __shfl_xor(scnt[k], 1); scnt[k] += __shfl_xor(scnt[k], 2); scnt[k] += __shfl_xor(scnt[k], 4);
  }
  sumd += __shfl_xor(sumd, 1); sumd += __shfl_xor(sumd, 2); sumd += __shfl_xor(sumd, 4);
  vcnt += __shfl_xor(vcnt, 1); vcnt += __shfl_xor(vcnt, 2); vcnt += __shfl_xor(vcnt, 4);
#pragma unroll
  for (int k = 0; k < 3; ++k) {
    dmin[k] = fminf(dmin[k], __shfl_xor(dmin[k], 1));
    dmin[k] = fminf(dmin[k], __shfl_xor(dmin[k], 2));
    dmin[k] = fminf(dmin[k], __shfl_xor(dmin[k], 4));
  }
#pragma unroll
  for (int k = 0; k < 8; ++k) {
    smin[k] = fminf(smin[k], __shfl_xor(smin[k], 1));
    smin[k] = fminf(smin[k], __shfl_xor(smin[k], 2));
    smin[k] = fminf(smin[k], __shfl_xor(smin[k], 4));
  }

  // ---- park row il's 33 feats in LDS (writer lane il*8 is in the same wave
  //      that consumes rows 8w..8w+7 below -> no barrier needed) ----
  if (jc == 0) {
    float* f = &xs[il * 33];
#pragma unroll
    for (int k = 0; k < 12; ++k) f[k] = cnt[k];
    f[12] = fminf(dmin[0] * 0.1f, 1.0f);
    f[13] = fminf(dmin[1] * 0.1f, 1.0f);
    f[14] = fminf(dmin[2] * 0.1f, 1.0f);
#pragma unroll
    for (int k = 0; k < 8; ++k) {
      f[15 + 2 * k] = scnt[k];
      f[16 + 2 * k] = fminf(smin[k] * 0.1f, 1.0f);
    }
    f[31] = cnt[9] + cnt[10] + cnt[11];
    f[32] = fminf(sumd / fmaxf(vcnt, 1.0f) * 0.1f, 1.0f);
  }

  // ======================= MLP section =======================
  const int w = tid >> 6;
  const int l = tid & 63;
  const float* __restrict__ xsf = xs + w * (RPW * 33);   // wave's 264 floats

  float xreg[5];
#pragma unroll
  for (int c = 0; c < 4; ++c) xreg[c] = xsf[c * 64 + l];
  xreg[4] = (l < 8) ? xsf[256 + l] : 0.0f;

  const v2f b1v = ((const v2f*)b1)[l];
  const v2f gav = ((const v2f*)gamma)[l];
  const v2f bev = ((const v2f*)beta)[l];
  const v2f b2v = ((const v2f*)b2)[l];
  const v2f* __restrict__ W1v = (const v2f*)W1;
  const v2f* __restrict__ W2v = (const v2f*)W2;

  // ---- phase 1: h = x @ W1 + b1 (readlane broadcast + packed fma) ----
  v2f h[RPW];
#pragma unroll
  for (int r = 0; r < RPW; ++r) h[r] = b1v;
#pragma unroll
  for (int k = 0; k < 33; ++k) {
    const v2f wv = W1v[k * 64 + l];
#pragma unroll
    for (int r = 0; r < RPW; ++r) {
      const int v = r * 33 + k;                 // compile-time
      pk_fma(h[r], rdlane(xreg[v >> 6], v & 63), wv);
    }
  }

  // ---- phase 2: LayerNorm + exact GELU (in registers) ----
  float g0[RPW], g1[RPW];
#pragma unroll
  for (int r = 0; r < RPW; ++r) {
    float s = h[r].x + h[r].y;
#pragma unroll
    for (int o = 32; o > 0; o >>= 1) s += __shfl_xor(s, o);
    const float mu = s * 0.0078125f;
    const float d0 = h[r].x - mu, d1 = h[r].y - mu;
    float v = d0 * d0 + d1 * d1;
#pragma unroll
    for (int o = 32; o > 0; o >>= 1) v += __shfl_xor(v, o);
    const float inv = 1.0f / __fsqrt_rn(v * 0.0078125f + 1e-5f);
    float a = d0 * inv * gav.x + bev.x;
    float bb = d1 * inv * gav.y + bev.y;
    g0[r] = 0.5f * a * (1.0f + erff(a * 0.70710678118654752f));
    g1[r] = 0.5f * bb * (1.0f + erff(bb * 0.70710678118654752f));
  }

  // ---- phase 3: out = g @ W2 + b2 (readlane broadcast + packed fma) ----
  v2f acc[RPW];
#pragma unroll
  for (int r = 0; r < RPW; ++r) acc[r] = b2v;
#pragma unroll 8
  for (int kp = 0; kp < 64; ++kp) {            // k = 2*kp, 2*kp+1
    const v2f wva = W2v[(2 * kp) * 64 + l];
    const v2f wvb = W2v[(2 * kp + 1) * 64 + l];
#pragma unroll
    for (int r = 0; r < RPW; ++r) {
      pk_fma(acc[r], rdlane(g0[r], kp), wva);
      pk_fma(acc[r], rdlane(g1[r], kp), wvb);
    }
  }
  const int row0 = blockIdx.x * 32 + w * RPW;  // == b*512 + i0 + w*8
#pragma unroll
  for (int r = 0; r < RPW; ++r) {
    ((v2f*)out)[(size_t)(row0 + r) * 64 + l] = acc[r];
  }
}

extern "C" void kernel_launch(void* const* d_in, const int* in_sizes, int n_in,
                              void* d_out, int out_size, void* d_ws, size_t ws_size,
                              hipStream_t stream) {
  const float* positions = (const float*)d_in[0];
  const void*  kpm_raw   = d_in[1];
  const float* W1    = (const float*)d_in[2];
  const float* b1    = (const float*)d_in[3];
  const float* gamma = (const float*)d_in[4];
  const float* beta  = (const float*)d_in[5];
  const float* W2    = (const float*)d_in[6];
  const float* b2    = (const float*)d_in[7];
  float* out = (float*)d_out;

  fused_kernel<<<NBATCH * 16, 256, 0, stream>>>(positions, kpm_raw,
      W1, b1, gamma, beta, W2, b2, out);
}